// Round 11
// baseline (941.912 us; speedup 1.0000x reference)
//
#include <hip/hip_runtime.h>
#include <hip/hip_bf16.h>
#include <stdint.h>

typedef __attribute__((ext_vector_type(8))) short bf16x8;
typedef __attribute__((ext_vector_type(4))) float f32x4v;
typedef __attribute__((ext_vector_type(16))) float f32x16;

#define CH_STRIDE 65536  // T*W*H

__device__ __forceinline__ uint16_t f2bf(float f) {
  uint32_t u = __builtin_bit_cast(uint32_t, f);
  u = (u + 0x7FFFu + ((u >> 16) & 1u)) >> 16;
  return (uint16_t)u;
}
__device__ __forceinline__ float bf2f(uint32_t b) {
  return __builtin_bit_cast(float, b << 16);
}
__device__ __forceinline__ uint16_t cvt_bf(float f) {
  return __builtin_bit_cast(uint16_t, __float2bfloat16(f));
}

#define MFMA32(a, b, c) __builtin_amdgcn_mfma_f32_32x32x16_bf16(a, b, c, 0, 0, 0)
#define LGKM0 asm volatile("s_waitcnt lgkmcnt(0)" ::: "memory")
#define BAR __builtin_amdgcn_s_barrier()
#define SCHED0 __builtin_amdgcn_sched_barrier(0)

#define LDSX_BYTES (6 * 8 * 66 * 16)  // 50688

__device__ __forceinline__ uint32_t swz(uint32_t b) {
  return b ^ (((b >> 7) & 7u) << 4);
}

__device__ __forceinline__ bf16x8 ldx(const uint8_t* ldsx, int r6, int oct, int ci) {
  return *(const bf16x8*)(ldsx + swz((uint32_t)((r6 * 8 + oct) * 66 + ci) * 16u));
}

__device__ __forceinline__ void stage_x(uint8_t* ldsx, const float* xs, int w0, int tid) {
  if (tid < 96) {
    int r6 = tid >> 4, rem = tid & 15;
    int oct = rem >> 1, side = rem & 1;
    bf16x8 z = {};
    *(bf16x8*)(ldsx + swz((uint32_t)((r6 * 8 + oct) * 66 + side * 65) * 16u)) = z;
  }
  #pragma unroll
  for (int k = 0; k < 3; ++k) {
    int u = tid + k * 256;
    int r6 = u >> 7, oct = (u >> 4) & 7, g = u & 15;
    int w = w0 - 1 + r6;
    uint32_t base = (uint32_t)((r6 * 8 + oct) * 66 + 4 * g + 1) * 16u;
    if ((unsigned)w < 64u) {
      const float* p = xs + (size_t)(oct * 8) * CH_STRIDE + w * 64 + 4 * g;
      f32x4v v[8];
      #pragma unroll
      for (int j = 0; j < 8; ++j) v[j] = *(const f32x4v*)(p + (size_t)j * CH_STRIDE);
      #pragma unroll
      for (int c = 0; c < 4; ++c) {
        bf16x8 frag;
        #pragma unroll
        for (int q = 0; q < 4; ++q) {
          frag[2 * q]     = (short)cvt_bf(v[2 * q][c]);
          frag[2 * q + 1] = (short)cvt_bf(v[2 * q + 1][c]);
        }
        *(bf16x8*)(ldsx + swz(base + (uint32_t)c * 16u)) = frag;
      }
    } else {
      bf16x8 z = {};
      #pragma unroll
      for (int c = 0; c < 4; ++c)
        *(bf16x8*)(ldsx + swz(base + (uint32_t)c * 16u)) = z;
    }
  }
}

__device__ __forceinline__ bf16x8 ldw_kv(const uint8_t* ldsw, int oct, int rowloc) {
  return *(const bf16x8*)(ldsw + (uint32_t)(oct * 128 + rowloc) * 16u);
}
__device__ __forceinline__ void ldw_g_kv(bf16x8* r, const uint16_t* wkv, int tap, int tid) {
  #pragma unroll
  for (int k = 0; k < 4; ++k)
    r[k] = *(const bf16x8*)(wkv + ((size_t)tap * 1024 + tid + k * 256) * 8);
}
__device__ __forceinline__ void stw_kv(uint8_t* ldsw, const bf16x8* r, int tid) {
  #pragma unroll
  for (int k = 0; k < 4; ++k)
    *(bf16x8*)(ldsw + (uint32_t)(tid + k * 256) * 16u) = r[k];
}

__device__ __forceinline__ bf16x8 ldw_q(const uint8_t* ldsw, int oct, int row) {
  return *(const bf16x8*)(ldsw + (uint32_t)(oct * 64 + row) * 16u);
}
__device__ __forceinline__ void ldw_g_q(bf16x8* r, const uint16_t* wq, int tap, int tid) {
  #pragma unroll
  for (int k = 0; k < 2; ++k)
    r[k] = *(const bf16x8*)(wq + ((size_t)tap * 512 + tid + k * 256) * 8);
}
__device__ __forceinline__ void stw_q(uint8_t* ldsw, const bf16x8* r, int tid) {
  #pragma unroll
  for (int k = 0; k < 2; ++k)
    *(bf16x8*)(ldsw + (uint32_t)(tid + k * 256) * 16u) = r[k];
}

// ---------------------------------------------------------------------------
__global__ void prep_weights(const float* __restrict__ wq, const float* __restrict__ wk,
                             const float* __restrict__ wv, uint16_t* __restrict__ wout) {
  int i = blockIdx.x * 256 + threadIdx.x;
  if (i >= 110592) return;
  if (i < 36864) {
    int tap = i >> 12, oct = (i >> 9) & 7, row = (i >> 3) & 63, j = i & 7;
    wout[i] = f2bf(wq[(row * 64 + oct * 8 + j) * 9 + tap]);
  } else {
    int m = i - 36864;
    int tap = m >> 13, oct = (m >> 10) & 7, rl = (m >> 3) & 127, j = m & 7;
    const float* src = (rl < 64) ? wk : wv;
    wout[i] = f2bf(src[((rl & 63) * 64 + oct * 8 + j) * 9 + tap]);
  }
}

// ---------------------------------------------------------------------------
// kv probe. V=0 full; V=1 no-epilogue; V=2 atomic->store; V=3 no-MFMA;
// V=4 no-global-loads. Identical structure otherwise (R9 157us kernel).
// ---------------------------------------------------------------------------
template <int V>
__global__ __launch_bounds__(256, 2) void kv_probe(
    const float* __restrict__ x, const uint16_t* __restrict__ wkv,
    const float* __restrict__ bk, const float* __restrict__ bv,
    float* __restrict__ s_out) {
  extern __shared__ uint8_t lds[];
  uint8_t* ldsx = lds;
  uint8_t* ldsw = lds + LDSX_BYTES;
  const int tid = threadIdx.x;
  const int l = tid & 63, ng = tid >> 6;
  int bid = (int)(blockIdx.x & 7) * 256 + (int)(blockIdx.x >> 3);
  const int rg = bid & 15, slice = bid >> 4;
  const int b = slice >> 4, t = slice & 15;
  const int w0 = rg * 4;
  const float* xs = x + ((size_t)b * 1024 + t) * 4096;
  const int lm = l & 31, lh = l >> 5;
  int isum = 0;

  if constexpr (V != 4) stage_x(ldsx, xs, w0, tid);
  bf16x8 r[4] = {};
  if constexpr (V != 4) ldw_g_kv(r, wkv, 0, tid);
  stw_kv(ldsw, r, tid);
  if constexpr (V != 4) ldw_g_kv(r, wkv, 1, tid);
  SCHED0; LGKM0; BAR; SCHED0;

  f32x16 accK[2][2], accV[2][2];
  #pragma unroll
  for (int mt = 0; mt < 2; ++mt)
    #pragma unroll
    for (int nt = 0; nt < 2; ++nt)
      #pragma unroll
      for (int q = 0; q < 16; ++q) { accK[mt][nt][q] = 0.f; accV[mt][nt][q] = 0.f; }

  #pragma unroll
  for (int tap = 0; tap < 9; ++tap) {
    const int dy = tap / 3, dx = tap % 3;
    __builtin_amdgcn_s_setprio(1);
    #pragma unroll
    for (int s = 0; s < 4; ++s) {
      int oct = s * 2 + lh;
      bf16x8 aK0 = ldw_kv(ldsw, oct, lm);
      bf16x8 aK1 = ldw_kv(ldsw, oct, 32 + lm);
      bf16x8 aV0 = ldw_kv(ldsw, oct, 64 + lm);
      bf16x8 aV1 = ldw_kv(ldsw, oct, 96 + lm);
      bf16x8 b0  = ldx(ldsx, ng + dy, oct, lm + dx);
      bf16x8 b1  = ldx(ldsx, ng + dy, oct, 32 + lm + dx);
      if constexpr (V == 3) {
        isum += (int)aK0[0] + (int)aK1[0] + (int)aV0[0] + (int)aV1[0]
              + (int)b0[0] + (int)b1[0];
      } else {
        accK[0][0] = MFMA32(aK0, b0, accK[0][0]);
        accK[0][1] = MFMA32(aK0, b1, accK[0][1]);
        accK[1][0] = MFMA32(aK1, b0, accK[1][0]);
        accK[1][1] = MFMA32(aK1, b1, accK[1][1]);
        accV[0][0] = MFMA32(aV0, b0, accV[0][0]);
        accV[0][1] = MFMA32(aV0, b1, accV[0][1]);
        accV[1][0] = MFMA32(aV1, b0, accV[1][0]);
        accV[1][1] = MFMA32(aV1, b1, accV[1][1]);
      }
    }
    __builtin_amdgcn_s_setprio(0);
    if (tap < 8) {
      SCHED0; BAR;
      stw_kv(ldsw, r, tid);
      if constexpr (V != 4) { if (tap < 7) ldw_g_kv(r, wkv, tap + 2, tid); }
      SCHED0; LGKM0; BAR; SCHED0;
    }
  }

  if constexpr (V == 0 || V == 3) {
    float* sb = s_out + (b * 16 + t) * 64;
    #pragma unroll
    for (int q = 0; q < 16; ++q) {
      int cl = (q & 3) + 8 * (q >> 2) + 4 * lh;
      #pragma unroll
      for (int mt = 0; mt < 2; ++mt) {
        int c = mt * 32 + cl;
        float bkc = bk[c], bvc = bv[c];
        float p = (accK[mt][0][q] + bkc) * (accV[mt][0][q] + bvc)
                + (accK[mt][1][q] + bkc) * (accV[mt][1][q] + bvc);
        #pragma unroll
        for (int m = 1; m < 32; m <<= 1) p += __shfl_xor(p, m, 64);
        if (lm == 0) atomicAdd(sb + c, p);
      }
    }
    if constexpr (V == 3) {
      if (l == 1) s_out[(size_t)blockIdx.x * 4 + ng] = (float)isum;  // keep loads live
    }
  } else if constexpr (V == 2) {
    #pragma unroll
    for (int q = 0; q < 16; ++q) {
      int cl = (q & 3) + 8 * (q >> 2) + 4 * lh;
      #pragma unroll
      for (int mt = 0; mt < 2; ++mt) {
        int c = mt * 32 + cl;
        float bkc = bk[c], bvc = bv[c];
        float p = (accK[mt][0][q] + bkc) * (accV[mt][0][q] + bvc)
                + (accK[mt][1][q] + bkc) * (accV[mt][1][q] + bvc);
        #pragma unroll
        for (int m = 1; m < 32; m <<= 1) p += __shfl_xor(p, m, 64);
        if (lm == 0) s_out[(size_t)blockIdx.x * 256 + ng * 64 + c] = p;  // store, no atomic
      }
    }
  } else {  // V==1, V==4: fold-store keeps all 8 accumulators live
    float fold = accK[0][0][0] + accK[0][1][1] + accK[1][0][2] + accK[1][1][3]
               + accV[0][0][4] + accV[0][1][5] + accV[1][0][6] + accV[1][1][7];
    if (l == 0) s_out[(size_t)blockIdx.x * 4 + ng] = fold;
  }
}

// ---------------------------------------------------------------------------
// Q kernel (R9, unchanged): produces d_out.
// ---------------------------------------------------------------------------
__global__ __launch_bounds__(256, 2) void q_out_kernel(
    const float* __restrict__ x, const uint16_t* __restrict__ wq,
    const float* __restrict__ bq, const float* __restrict__ s_in,
    const float* __restrict__ gamma, float* __restrict__ out) {
  extern __shared__ uint8_t lds[];
  uint8_t* ldsx = lds;
  uint8_t* ldsw = lds + LDSX_BYTES;
  const int tid = threadIdx.x;
  const int l = tid & 63, ng = tid >> 6;
  int bid = (int)(blockIdx.x & 7) * 256 + (int)(blockIdx.x >> 3);
  const int rg = bid & 15, slice = bid >> 4;
  const int b = slice >> 4, t = slice & 15;
  const int w0 = rg * 4;
  const float* xs = x + ((size_t)b * 1024 + t) * 4096;
  const int lm = l & 31, lh = l >> 5;

  stage_x(ldsx, xs, w0, tid);
  bf16x8 r[2];
  ldw_g_q(r, wq, 0, tid);
  stw_q(ldsw, r, tid);
  ldw_g_q(r, wq, 1, tid);
  SCHED0; LGKM0; BAR; SCHED0;

  f32x16 acc[2][2];
  #pragma unroll
  for (int mt = 0; mt < 2; ++mt)
    #pragma unroll
    for (int nt = 0; nt < 2; ++nt)
      #pragma unroll
      for (int q = 0; q < 16; ++q) acc[mt][nt][q] = 0.f;

  #pragma unroll
  for (int tap = 0; tap < 9; ++tap) {
    const int dy = tap / 3, dx = tap % 3;
    __builtin_amdgcn_s_setprio(1);
    #pragma unroll
    for (int s = 0; s < 4; ++s) {
      int oct = s * 2 + lh;
      bf16x8 a0 = ldw_q(ldsw, oct, lm);
      bf16x8 a1 = ldw_q(ldsw, oct, 32 + lm);
      bf16x8 b0 = ldx(ldsx, ng + dy, oct, lm + dx);
      bf16x8 b1 = ldx(ldsx, ng + dy, oct, 32 + lm + dx);
      acc[0][0] = MFMA32(a0, b0, acc[0][0]);
      acc[0][1] = MFMA32(a0, b1, acc[0][1]);
      acc[1][0] = MFMA32(a1, b0, acc[1][0]);
      acc[1][1] = MFMA32(a1, b1, acc[1][1]);
    }
    __builtin_amdgcn_s_setprio(0);
    if (tap < 8) {
      SCHED0; BAR;
      stw_q(ldsw, r, tid);
      if (tap < 7) ldw_g_q(r, wq, tap + 2, tid);
      SCHED0; LGKM0; BAR; SCHED0;
    }
  }

  float g = gamma[0];
  const float* sb = s_in + (b * 16 + t) * 64;
  int w = w0 + ng;
  #pragma unroll
  for (int mt = 0; mt < 2; ++mt) {
    #pragma unroll
    for (int q = 0; q < 16; ++q) {
      int cl = (q & 3) + 8 * (q >> 2) + 4 * lh;
      int c  = mt * 32 + cl;
      float qb = bq[c], sc = sb[c];
      #pragma unroll
      for (int nt = 0; nt < 2; ++nt) {
        int h = nt * 32 + lm;
        uint32_t xb = (uint32_t)(((ng + 1) * 8 + (c >> 3)) * 66 + (h + 1)) * 16u
                    + (uint32_t)(c & 7) * 2u;
        float xv = bf2f(*(const uint16_t*)(ldsx + swz(xb)));
        size_t idx = ((size_t)(b * 64 + c) * 16 + t) * 4096 + (size_t)w * 64 + h;
        out[idx] = g * (acc[mt][nt][q] + qb) * sc + xv;
      }
    }
  }
}

extern "C" void kernel_launch(void* const* d_in, const int* in_sizes, int n_in,
                              void* d_out, int out_size, void* d_ws, size_t ws_size,
                              hipStream_t stream) {
  const float* x   = (const float*)d_in[0];
  const float* wq  = (const float*)d_in[1];
  const float* wk  = (const float*)d_in[2];
  const float* wv  = (const float*)d_in[3];
  const float* bq  = (const float*)d_in[4];
  const float* bk  = (const float*)d_in[5];
  const float* bv  = (const float*)d_in[6];
  const float* gam = (const float*)d_in[7];

  uint16_t* wbf   = (uint16_t*)d_ws;                    // 221184 B
  float* sbuf     = (float*)((uint8_t*)d_ws + 221184);  // 32 KB
  float* pscratch = (float*)((uint8_t*)d_ws + 262144);  // 2+ MB probe scratch

  hipMemsetAsync(sbuf, 0, 8 * 16 * 64 * sizeof(float), stream);
  prep_weights<<<(110592 + 255) / 256, 256, 0, stream>>>(wq, wk, wv, wbf);
  // Real path:
  kv_probe<0><<<2048, 256, LDSX_BYTES + 16384, stream>>>(x, wbf + 36864, bk, bv, sbuf);
  q_out_kernel<<<2048, 256, LDSX_BYTES + 8192, stream>>>(x, wbf, bq, sbuf, gam, (float*)d_out);
  // Diagnostic probes (write scratch only; read per-dispatch dur_us from rocprof):
  kv_probe<1><<<2048, 256, LDSX_BYTES + 16384, stream>>>(x, wbf + 36864, bk, bv, pscratch);
  kv_probe<2><<<2048, 256, LDSX_BYTES + 16384, stream>>>(x, wbf + 36864, bk, bv, pscratch);
  kv_probe<3><<<2048, 256, LDSX_BYTES + 16384, stream>>>(x, wbf + 36864, bk, bv, pscratch);
  kv_probe<4><<<2048, 256, LDSX_BYTES + 16384, stream>>>(x, wbf + 36864, bk, bv, pscratch);
}

// Round 13
// 156.040 us; speedup vs baseline: 6.0364x; 6.0364x over previous
//
#include <hip/hip_runtime.h>
#include <hip/hip_bf16.h>
#include <stdint.h>

typedef __attribute__((ext_vector_type(8))) short bf16x8;
typedef __attribute__((ext_vector_type(4))) float f32x4v;
typedef __attribute__((ext_vector_type(16))) float f32x16;

#define CH_STRIDE 65536  // T*W*H

__device__ __forceinline__ uint16_t f2bf(float f) {
  uint32_t u = __builtin_bit_cast(uint32_t, f);
  u = (u + 0x7FFFu + ((u >> 16) & 1u)) >> 16;
  return (uint16_t)u;
}
__device__ __forceinline__ float bf2f(uint32_t b) {
  return __builtin_bit_cast(float, b << 16);
}
__device__ __forceinline__ uint16_t cvt_bf(float f) {
  return __builtin_bit_cast(uint16_t, __float2bfloat16(f));
}

#define MFMA32(a, b, c) __builtin_amdgcn_mfma_f32_32x32x16_bf16(a, b, c, 0, 0, 0)
#define LGKM0 asm volatile("s_waitcnt lgkmcnt(0)" ::: "memory")
#define BAR __builtin_amdgcn_s_barrier()
#define SCHED0 __builtin_amdgcn_sched_barrier(0)

#define LDSX_BYTES (6 * 8 * 66 * 16)  // 50688

__device__ __forceinline__ uint32_t swz(uint32_t b) {
  return b ^ (((b >> 7) & 7u) << 4);
}

__device__ __forceinline__ bf16x8 ldx(const uint8_t* ldsx, int r6, int oct, int ci) {
  return *(const bf16x8*)(ldsx + swz((uint32_t)((r6 * 8 + oct) * 66 + ci) * 16u));
}

__device__ __forceinline__ void stage_x(uint8_t* ldsx, const float* xs, int w0, int tid) {
  if (tid < 96) {
    int r6 = tid >> 4, rem = tid & 15;
    int oct = rem >> 1, side = rem & 1;
    bf16x8 z = {};
    *(bf16x8*)(ldsx + swz((uint32_t)((r6 * 8 + oct) * 66 + side * 65) * 16u)) = z;
  }
  #pragma unroll
  for (int k = 0; k < 3; ++k) {
    int u = tid + k * 256;
    int r6 = u >> 7, oct = (u >> 4) & 7, g = u & 15;
    int w = w0 - 1 + r6;
    uint32_t base = (uint32_t)((r6 * 8 + oct) * 66 + 4 * g + 1) * 16u;
    if ((unsigned)w < 64u) {
      const float* p = xs + (size_t)(oct * 8) * CH_STRIDE + w * 64 + 4 * g;
      f32x4v v[8];
      #pragma unroll
      for (int j = 0; j < 8; ++j) v[j] = *(const f32x4v*)(p + (size_t)j * CH_STRIDE);
      #pragma unroll
      for (int c = 0; c < 4; ++c) {
        bf16x8 frag;
        #pragma unroll
        for (int q = 0; q < 4; ++q) {
          frag[2 * q]     = (short)cvt_bf(v[2 * q][c]);
          frag[2 * q + 1] = (short)cvt_bf(v[2 * q + 1][c]);
        }
        *(bf16x8*)(ldsx + swz(base + (uint32_t)c * 16u)) = frag;
      }
    } else {
      bf16x8 z = {};
      #pragma unroll
      for (int c = 0; c < 4; ++c)
        *(bf16x8*)(ldsx + swz(base + (uint32_t)c * 16u)) = z;
    }
  }
}

__device__ __forceinline__ bf16x8 ldw_kv(const uint8_t* ldsw, int oct, int rowloc) {
  return *(const bf16x8*)(ldsw + (uint32_t)(oct * 128 + rowloc) * 16u);
}
__device__ __forceinline__ void ldw_g_kv(bf16x8* r, const uint16_t* wkv, int tap, int tid) {
  #pragma unroll
  for (int k = 0; k < 4; ++k)
    r[k] = *(const bf16x8*)(wkv + ((size_t)tap * 1024 + tid + k * 256) * 8);
}
__device__ __forceinline__ void stw_kv(uint8_t* ldsw, const bf16x8* r, int tid) {
  #pragma unroll
  for (int k = 0; k < 4; ++k)
    *(bf16x8*)(ldsw + (uint32_t)(tid + k * 256) * 16u) = r[k];
}

__device__ __forceinline__ bf16x8 ldw_q(const uint8_t* ldsw, int oct, int row) {
  return *(const bf16x8*)(ldsw + (uint32_t)(oct * 64 + row) * 16u);
}
__device__ __forceinline__ void ldw_g_q(bf16x8* r, const uint16_t* wq, int tap, int tid) {
  #pragma unroll
  for (int k = 0; k < 2; ++k)
    r[k] = *(const bf16x8*)(wq + ((size_t)tap * 512 + tid + k * 256) * 8);
}
__device__ __forceinline__ void stw_q(uint8_t* ldsw, const bf16x8* r, int tid) {
  #pragma unroll
  for (int k = 0; k < 2; ++k)
    *(bf16x8*)(ldsw + (uint32_t)(tid + k * 256) * 16u) = r[k];
}

// ---------------------------------------------------------------------------
__global__ void prep_weights(const float* __restrict__ wq, const float* __restrict__ wk,
                             const float* __restrict__ wv, uint16_t* __restrict__ wout) {
  int i = blockIdx.x * 256 + threadIdx.x;
  if (i >= 110592) return;
  if (i < 36864) {
    int tap = i >> 12, oct = (i >> 9) & 7, row = (i >> 3) & 63, j = i & 7;
    wout[i] = f2bf(wq[(row * 64 + oct * 8 + j) * 9 + tap]);
  } else {
    int m = i - 36864;
    int tap = m >> 13, oct = (m >> 10) & 7, rl = (m >> 3) & 127, j = m & 7;
    const float* src = (rl < 64) ? wk : wv;
    wout[i] = f2bf(src[((rl & 63) * 64 + oct * 8 + j) * 9 + tap]);
  }
}

// ---------------------------------------------------------------------------
// KV kernel (R9 structure). Epilogue: shfl+atomic -> LDS partial-dump +
// 64-thread reduce + one atomicAdd per channel.
// ---------------------------------------------------------------------------
__global__ __launch_bounds__(256, 2) void kv_s_kernel(
    const float* __restrict__ x, const uint16_t* __restrict__ wkv,
    const float* __restrict__ bk, const float* __restrict__ bv,
    float* __restrict__ s_out) {
  extern __shared__ uint8_t lds[];
  uint8_t* ldsx = lds;
  uint8_t* ldsw = lds + LDSX_BYTES;
  const int tid = threadIdx.x;
  const int l = tid & 63, ng = tid >> 6;
  int bid = (int)(blockIdx.x & 7) * 256 + (int)(blockIdx.x >> 3);  // XCD swizzle
  const int rg = bid & 15, slice = bid >> 4;
  const int b = slice >> 4, t = slice & 15;
  const int w0 = rg * 4;
  const float* xs = x + ((size_t)b * 1024 + t) * 4096;
  const int lm = l & 31, lh = l >> 5;

  stage_x(ldsx, xs, w0, tid);
  bf16x8 r[4];
  ldw_g_kv(r, wkv, 0, tid);
  stw_kv(ldsw, r, tid);
  ldw_g_kv(r, wkv, 1, tid);
  SCHED0; LGKM0; BAR; SCHED0;

  f32x16 accK[2][2], accV[2][2];
  #pragma unroll
  for (int mt = 0; mt < 2; ++mt)
    #pragma unroll
    for (int nt = 0; nt < 2; ++nt)
      #pragma unroll
      for (int q = 0; q < 16; ++q) { accK[mt][nt][q] = 0.f; accV[mt][nt][q] = 0.f; }

  #pragma unroll
  for (int tap = 0; tap < 9; ++tap) {
    const int dy = tap / 3, dx = tap % 3;
    __builtin_amdgcn_s_setprio(1);
    #pragma unroll
    for (int s = 0; s < 4; ++s) {
      int oct = s * 2 + lh;
      bf16x8 aK0 = ldw_kv(ldsw, oct, lm);
      bf16x8 aK1 = ldw_kv(ldsw, oct, 32 + lm);
      bf16x8 aV0 = ldw_kv(ldsw, oct, 64 + lm);
      bf16x8 aV1 = ldw_kv(ldsw, oct, 96 + lm);
      bf16x8 b0  = ldx(ldsx, ng + dy, oct, lm + dx);
      bf16x8 b1  = ldx(ldsx, ng + dy, oct, 32 + lm + dx);
      accK[0][0] = MFMA32(aK0, b0, accK[0][0]);
      accK[0][1] = MFMA32(aK0, b1, accK[0][1]);
      accK[1][0] = MFMA32(aK1, b0, accK[1][0]);
      accK[1][1] = MFMA32(aK1, b1, accK[1][1]);
      accV[0][0] = MFMA32(aV0, b0, accV[0][0]);
      accV[0][1] = MFMA32(aV0, b1, accV[0][1]);
      accV[1][0] = MFMA32(aV1, b0, accV[1][0]);
      accV[1][1] = MFMA32(aV1, b1, accV[1][1]);
    }
    __builtin_amdgcn_s_setprio(0);
    if (tap < 8) {
      SCHED0; BAR;
      stw_kv(ldsw, r, tid);
      if (tap < 7) ldw_g_kv(r, wkv, tap + 2, tid);
      SCHED0; LGKM0; BAR; SCHED0;
    }
  }

  // ---- epilogue: dump per-lane partials to LDS, reduce, 1 atomic per ch ----
  __syncthreads();                         // x-tile dead; safe to reuse ldsx
  float* red = (float*)ldsx;               // [c][132] f32 (pad vs bank aliasing)
  #pragma unroll
  for (int q = 0; q < 16; ++q) {
    int cl = (q & 3) + 8 * (q >> 2) + 4 * lh;
    #pragma unroll
    for (int mt = 0; mt < 2; ++mt) {
      int c = mt * 32 + cl;
      float bkc = bk[c], bvc = bv[c];
      float p = (accK[mt][0][q] + bkc) * (accV[mt][0][q] + bvc)
              + (accK[mt][1][q] + bkc) * (accV[mt][1][q] + bvc);
      red[c * 132 + ng * 32 + lm] = p;
    }
  }
  __syncthreads();
  if (tid < 64) {
    const f32x4v* rp = (const f32x4v*)(red + tid * 132);
    f32x4v a4 = {0.f, 0.f, 0.f, 0.f};
    #pragma unroll
    for (int j = 0; j < 32; ++j) a4 += rp[j];
    atomicAdd(s_out + (b * 16 + t) * 64 + tid, a4[0] + a4[1] + a4[2] + a4[3]);
  }
}

// ---------------------------------------------------------------------------
// Q kernel (R9, unchanged).
// ---------------------------------------------------------------------------
__global__ __launch_bounds__(256, 2) void q_out_kernel(
    const float* __restrict__ x, const uint16_t* __restrict__ wq,
    const float* __restrict__ bq, const float* __restrict__ s_in,
    const float* __restrict__ gamma, float* __restrict__ out) {
  extern __shared__ uint8_t lds[];
  uint8_t* ldsx = lds;
  uint8_t* ldsw = lds + LDSX_BYTES;
  const int tid = threadIdx.x;
  const int l = tid & 63, ng = tid >> 6;
  int bid = (int)(blockIdx.x & 7) * 256 + (int)(blockIdx.x >> 3);  // XCD swizzle
  const int rg = bid & 15, slice = bid >> 4;
  const int b = slice >> 4, t = slice & 15;
  const int w0 = rg * 4;
  const float* xs = x + ((size_t)b * 1024 + t) * 4096;
  const int lm = l & 31, lh = l >> 5;

  stage_x(ldsx, xs, w0, tid);
  bf16x8 r[2];
  ldw_g_q(r, wq, 0, tid);
  stw_q(ldsw, r, tid);
  ldw_g_q(r, wq, 1, tid);
  SCHED0; LGKM0; BAR; SCHED0;

  f32x16 acc[2][2];
  #pragma unroll
  for (int mt = 0; mt < 2; ++mt)
    #pragma unroll
    for (int nt = 0; nt < 2; ++nt)
      #pragma unroll
      for (int q = 0; q < 16; ++q) acc[mt][nt][q] = 0.f;

  #pragma unroll
  for (int tap = 0; tap < 9; ++tap) {
    const int dy = tap / 3, dx = tap % 3;
    __builtin_amdgcn_s_setprio(1);
    #pragma unroll
    for (int s = 0; s < 4; ++s) {
      int oct = s * 2 + lh;
      bf16x8 a0 = ldw_q(ldsw, oct, lm);
      bf16x8 a1 = ldw_q(ldsw, oct, 32 + lm);
      bf16x8 b0 = ldx(ldsx, ng + dy, oct, lm + dx);
      bf16x8 b1 = ldx(ldsx, ng + dy, oct, 32 + lm + dx);
      acc[0][0] = MFMA32(a0, b0, acc[0][0]);
      acc[0][1] = MFMA32(a0, b1, acc[0][1]);
      acc[1][0] = MFMA32(a1, b0, acc[1][0]);
      acc[1][1] = MFMA32(a1, b1, acc[1][1]);
    }
    __builtin_amdgcn_s_setprio(0);
    if (tap < 8) {
      SCHED0; BAR;
      stw_q(ldsw, r, tid);
      if (tap < 7) ldw_g_q(r, wq, tap + 2, tid);
      SCHED0; LGKM0; BAR; SCHED0;
    }
  }

  float g = gamma[0];
  const float* sb = s_in + (b * 16 + t) * 64;
  int w = w0 + ng;
  #pragma unroll
  for (int mt = 0; mt < 2; ++mt) {
    #pragma unroll
    for (int q = 0; q < 16; ++q) {
      int cl = (q & 3) + 8 * (q >> 2) + 4 * lh;
      int c  = mt * 32 + cl;
      float qb = bq[c], sc = sb[c];
      #pragma unroll
      for (int nt = 0; nt < 2; ++nt) {
        int h = nt * 32 + lm;
        uint32_t xb = (uint32_t)(((ng + 1) * 8 + (c >> 3)) * 66 + (h + 1)) * 16u
                    + (uint32_t)(c & 7) * 2u;
        float xv = bf2f(*(const uint16_t*)(ldsx + swz(xb)));
        size_t idx = ((size_t)(b * 64 + c) * 16 + t) * 4096 + (size_t)w * 64 + h;
        out[idx] = g * (acc[mt][nt][q] + qb) * sc + xv;
      }
    }
  }
}

extern "C" void kernel_launch(void* const* d_in, const int* in_sizes, int n_in,
                              void* d_out, int out_size, void* d_ws, size_t ws_size,
                              hipStream_t stream) {
  const float* x   = (const float*)d_in[0];
  const float* wq  = (const float*)d_in[1];
  const float* wk  = (const float*)d_in[2];
  const float* wv  = (const float*)d_in[3];
  const float* bq  = (const float*)d_in[4];
  const float* bk  = (const float*)d_in[5];
  const float* bv  = (const float*)d_in[6];
  const float* gam = (const float*)d_in[7];

  uint16_t* wbf = (uint16_t*)d_ws;                    // 221184 B
  float* sbuf   = (float*)((uint8_t*)d_ws + 221184);  // 32 KB

  hipMemsetAsync(sbuf, 0, 8 * 16 * 64 * sizeof(float), stream);
  prep_weights<<<(110592 + 255) / 256, 256, 0, stream>>>(wq, wk, wv, wbf);
  kv_s_kernel<<<2048, 256, LDSX_BYTES + 16384, stream>>>(x, wbf + 36864, bk, bv, sbuf);
  q_out_kernel<<<2048, 256, LDSX_BYTES + 8192, stream>>>(x, wbf, bq, sbuf, gam, (float*)d_out);
}